// Round 1
// 506.329 us; speedup vs baseline: 1.0029x; 1.0029x over previous
//
#include <hip/hip_runtime.h>

#define N_NODES 100000
#define N_EDGES 1600000
#define SCAN_NB ((N_NODES + 255) / 256)   // 391

// packed degree: bits 63..52 = count, bits 51..0 = sum(w) in 2^-32 fixed point
#define CNT_SHIFT 52
#define WSUM_MASK ((1ULL << 52) - 1)

typedef __attribute__((ext_vector_type(8))) short short8;   // MFMA A/B frag (8 bf16)
typedef __attribute__((ext_vector_type(4))) float f32x4;    // MFMA C/D frag

__device__ inline unsigned short f2bf(float f) {   // round-to-nearest-even
    unsigned int u = __float_as_uint(f);
    u += 0x7FFFu + ((u >> 16) & 1u);
    return (unsigned short)(u >> 16);
}
__device__ inline float bflo(unsigned int u) { return __uint_as_float(u << 16); }
__device__ inline float bfhi(unsigned int u) { return __uint_as_float(u & 0xFFFF0000u); }
__device__ inline float bf2f(unsigned short h) { return __uint_as_float((unsigned int)h << 16); }

// ---------------- CSR build ----------------

__global__ void init_packed_kernel(unsigned long long* __restrict__ packed, int n) {
    int i = blockIdx.x * blockDim.x + threadIdx.x;
    if (i < n) packed[i] = 1ULL << 32;   // self-loop weight 1.0, count 0
}

__global__ void edge_pass1_kernel(const int* __restrict__ dst, const float* __restrict__ w,
                                  unsigned long long* __restrict__ packed,
                                  int* __restrict__ rank, int E) {
    int e = blockIdx.x * blockDim.x + threadIdx.x;
    if (e < E) {
        int d = dst[e];
        unsigned long long inc = (1ULL << CNT_SHIFT)
                               + (unsigned long long)((double)w[e] * 4294967296.0);
        unsigned long long old = atomicAdd(&packed[d], inc);
        rank[e] = (int)(old >> CNT_SHIFT);
    }
}

// scan1 fused with extract: packed -> cnt, dinv, block sums
__global__ __launch_bounds__(256) void scan1_kernel(const unsigned long long* __restrict__ packed,
                                                    int* __restrict__ cnt, float* __restrict__ dinv,
                                                    int* __restrict__ bsum, int n) {
    __shared__ int s[256];
    int tid = threadIdx.x;
    int i = blockIdx.x * 256 + tid;
    int v = 0;
    if (i < n) {
        unsigned long long pk = packed[i];
        v = (int)(pk >> CNT_SHIFT);
        cnt[i] = v;
        float sum = (float)((double)(pk & WSUM_MASK) * (1.0 / 4294967296.0));
        dinv[i] = rsqrtf(sum);   // sum >= 1 always
    }
    s[tid] = v;
    __syncthreads();
    #pragma unroll
    for (int off = 128; off > 0; off >>= 1) {
        if (tid < off) s[tid] += s[tid + off];
        __syncthreads();
    }
    if (tid == 0) bsum[blockIdx.x] = s[0];
}

__global__ __launch_bounds__(512) void scan2_kernel(int* __restrict__ bsum, int nb) {
    __shared__ int s[512];
    int tid = threadIdx.x;
    int v = (tid < nb) ? bsum[tid] : 0;
    s[tid] = v;
    __syncthreads();
    #pragma unroll
    for (int off = 1; off < 512; off <<= 1) {
        int t = s[tid];
        int u = (tid >= off) ? s[tid - off] : 0;
        __syncthreads();
        s[tid] = t + u;
        __syncthreads();
    }
    if (tid < nb) bsum[tid] = (tid == 0) ? 0 : s[tid - 1];
}

__global__ __launch_bounds__(256) void scan3_kernel(const int* __restrict__ cnt,
                                                    const int* __restrict__ bsum,
                                                    int* __restrict__ rowptr, int n) {
    __shared__ int s[256];
    int tid = threadIdx.x;
    int i = blockIdx.x * 256 + tid;
    int v = (i < n) ? cnt[i] : 0;
    s[tid] = v;
    __syncthreads();
    #pragma unroll
    for (int off = 1; off < 256; off <<= 1) {
        int t = s[tid];
        int u = (tid >= off) ? s[tid - off] : 0;
        __syncthreads();
        s[tid] = t + u;
        __syncthreads();
    }
    if (i < n) rowptr[i] = bsum[blockIdx.x] + s[tid] - v;
    if (i == 0) rowptr[n] = N_EDGES;
}

// interleaved edge record: low dword = src, high dword = norm bits
__global__ void place_kernel(const int* __restrict__ src, const int* __restrict__ dst,
                             const float* __restrict__ w, const float* __restrict__ dinv,
                             const int* __restrict__ rowptr, const int* __restrict__ rank,
                             unsigned long long* __restrict__ edges, int E) {
    int e = blockIdx.x * blockDim.x + threadIdx.x;
    if (e < E) {
        int s = src[e], d = dst[e];
        int pos = rowptr[d] + rank[e];
        float nrm = dinv[s] * w[e] * dinv[d];
        unsigned long long rec = ((unsigned long long)__float_as_uint(nrm) << 32)
                               | (unsigned int)s;
        edges[pos] = rec;
    }
}

// ---------------- MFMA GEMM: H(bf16) = A @ W,  K=128 fixed ----------------
// Block: 128 rows x FOUT cols, 256 threads (4 waves x 32 rows).
// A-fragments loaded straight from global (16B/lane). W split hi/lo bf16 into LDS,
// transposed n-major, stride 136 shorts (16B-aligned frags, uniform 8-way b128).
// AF32: A is f32 -> in-register split, 3rd pass Alo@Whi recovers f32 accuracy.

#define BSTR 136

template<int NCT, int FOUT, int HSTRIDE, bool AF32>
__global__ __launch_bounds__(256) void gemm_mfma_kernel(
        const void* __restrict__ Ain, const float* __restrict__ W,
        unsigned short* __restrict__ Hout, int M) {
    __shared__ unsigned short sBhi[NCT * 16 * BSTR];
    __shared__ unsigned short sBlo[NCT * 16 * BSTR];
    int tid = threadIdx.x;

    if (FOUT != NCT * 16) {   // zero-pad unused B columns
        unsigned int* z0 = (unsigned int*)sBhi;
        unsigned int* z1 = (unsigned int*)sBlo;
        for (int i = tid; i < NCT * 16 * BSTR / 2; i += 256) { z0[i] = 0u; z1[i] = 0u; }
        __syncthreads();
    }
    // stage W (K=128 x FOUT, row-major) -> split bf16, transposed [n][k]
    for (int i = tid; i < 128 * FOUT; i += 256) {
        int k = i / FOUT, n = i - k * FOUT;
        float v = W[i];
        unsigned short hi = f2bf(v);
        unsigned short lo = f2bf(v - bf2f(hi));
        sBhi[n * BSTR + k] = hi;
        sBlo[n * BSTR + k] = lo;
    }
    __syncthreads();

    int lane = tid & 63;
    int m16 = lane & 15;
    int q = lane >> 4;
    int wv = tid >> 6;
    int wbase = blockIdx.x * 128 + wv * 32;

    // A fragments: 2 row-tiles x 4 k-steps, from global
    short8 afr[2][4];
    short8 alo[2][4];
    #pragma unroll
    for (int mt = 0; mt < 2; mt++) {
        int row = wbase + mt * 16 + m16;
        row = (row < M) ? row : (M - 1);   // clamp: no OOB fault, stores guarded
        if (AF32) {
            const float* ar = (const float*)Ain + (size_t)row * 128;
            #pragma unroll
            for (int kt = 0; kt < 4; kt++) {
                const float* p = ar + kt * 32 + q * 8;
                float4 a = *(const float4*)p;
                float4 b = *(const float4*)(p + 4);
                float vv[8] = {a.x, a.y, a.z, a.w, b.x, b.y, b.z, b.w};
                short8 h, l;
                #pragma unroll
                for (int j = 0; j < 8; j++) {
                    unsigned short hb = f2bf(vv[j]);
                    h[j] = (short)hb;
                    l[j] = (short)f2bf(vv[j] - bf2f(hb));
                }
                afr[mt][kt] = h;
                alo[mt][kt] = l;
            }
        } else {
            const unsigned short* ar = (const unsigned short*)Ain + (size_t)row * 128;
            #pragma unroll
            for (int kt = 0; kt < 4; kt++) {
                afr[mt][kt] = *(const short8*)(ar + kt * 32 + q * 8);
            }
        }
    }

    f32x4 acc[2][NCT] = {};
    #pragma unroll
    for (int kt = 0; kt < 4; kt++) {
        #pragma unroll
        for (int ct = 0; ct < NCT; ct++) {
            const unsigned short* bp = &sBhi[(ct * 16 + m16) * BSTR + kt * 32 + q * 8];
            short8 bh = *(const short8*)bp;
            short8 bl = *(const short8*)&sBlo[(ct * 16 + m16) * BSTR + kt * 32 + q * 8];
            #pragma unroll
            for (int mt = 0; mt < 2; mt++) {
                acc[mt][ct] = __builtin_amdgcn_mfma_f32_16x16x32_bf16(afr[mt][kt], bh, acc[mt][ct], 0, 0, 0);
                acc[mt][ct] = __builtin_amdgcn_mfma_f32_16x16x32_bf16(afr[mt][kt], bl, acc[mt][ct], 0, 0, 0);
                if (AF32)
                    acc[mt][ct] = __builtin_amdgcn_mfma_f32_16x16x32_bf16(alo[mt][kt], bh, acc[mt][ct], 0, 0, 0);
            }
        }
    }

    // epilogue: C/D layout col=lane&15, row=(lane>>4)*4+reg
    #pragma unroll
    for (int mt = 0; mt < 2; mt++) {
        #pragma unroll
        for (int ct = 0; ct < NCT; ct++) {
            int col = ct * 16 + m16;
            if (FOUT != NCT * 16 && col >= FOUT) continue;
            #pragma unroll
            for (int r = 0; r < 4; r++) {
                int row = wbase + mt * 16 + q * 4 + r;
                if (row < M)
                    Hout[(size_t)row * HSTRIDE + col] = f2bf(acc[mt][ct][r]);
            }
        }
    }
}

// ---------------- Aggregation F=128 (bf16 H, bf16 out) ----------------
// v2: one wave/node, 4x 16-lane groups, dwordx4 per lane (4 rows per load
// instruction), predicated 8-slot iterations (no serial tail: inactive slots
// load the node's own row with w=0 -> L1/L2-hot, keeps MLP at 8 rows).
// Self-loop folded in as a g==0 accumulation of an early-issued self-row load.
// Cross-group reduce: shfl_xor 16/32; lanes 0-15 bias/relu/pack/store 16B each.

template<bool RELU>
__global__ __launch_bounds__(256) void gather128v2_kernel(
        const unsigned int* __restrict__ Hd,                // N x 64 dwords (bf16x2)
        const int* __restrict__ rowptr,
        const unsigned long long* __restrict__ edges,       // (src, normbits)
        const float* __restrict__ dinv, const float* __restrict__ bias,
        unsigned int* __restrict__ outd, int n) {           // N x 64 dwords (bf16x2)
    int wave = threadIdx.x >> 6;
    int lane = threadIdx.x & 63;
    int node = blockIdx.x * 4 + wave;
    if (node >= n) return;
    const uint4* H = (const uint4*)Hd;                      // row = 16 uint4
    int beg = __builtin_amdgcn_readfirstlane(rowptr[node]);
    int end = __builtin_amdgcn_readfirstlane(rowptr[node + 1]);
    int deg = end - beg;
    float di = dinv[node];
    int g  = lane >> 4;      // edge-slot group 0..3
    int sl = lane & 15;      // 16B chunk within row

    uint4 us = H[(size_t)node * 16 + sl];   // self row, issued early (also the
    float ws = (g == 0) ? di * di : 0.f;    // target of predicated-off slots)

    float acc[8] = {0.f, 0.f, 0.f, 0.f, 0.f, 0.f, 0.f, 0.f};

    for (int base = 0; base < deg; base += 8) {
        #pragma unroll
        for (int u = 0; u < 2; u++) {
            int slot = base + g * 2 + u;
            bool real = slot < deg;
            unsigned long long rec = edges[real ? (beg + slot) : 0];
            int s  = real ? (int)(unsigned int)rec : node;
            float w = real ? __uint_as_float((unsigned int)(rec >> 32)) : 0.f;
            uint4 q = H[(size_t)s * 16 + sl];
            acc[0] += w * bflo(q.x); acc[1] += w * bfhi(q.x);
            acc[2] += w * bflo(q.y); acc[3] += w * bfhi(q.y);
            acc[4] += w * bflo(q.z); acc[5] += w * bfhi(q.z);
            acc[6] += w * bflo(q.w); acc[7] += w * bfhi(q.w);
        }
    }

    // self-loop contribution (only group 0 carries it)
    acc[0] += ws * bflo(us.x); acc[1] += ws * bfhi(us.x);
    acc[2] += ws * bflo(us.y); acc[3] += ws * bfhi(us.y);
    acc[4] += ws * bflo(us.z); acc[5] += ws * bfhi(us.z);
    acc[6] += ws * bflo(us.w); acc[7] += ws * bfhi(us.w);

    // reduce across the 4 groups (lanes sl, sl+16, sl+32, sl+48)
    #pragma unroll
    for (int j = 0; j < 8; j++) {
        acc[j] += __shfl_xor(acc[j], 16);
        acc[j] += __shfl_xor(acc[j], 32);
    }

    if (lane < 16) {
        const float4* b4 = (const float4*)bias;
        float4 b0 = b4[sl * 2], b1 = b4[sl * 2 + 1];
        acc[0] += b0.x; acc[1] += b0.y; acc[2] += b0.z; acc[3] += b0.w;
        acc[4] += b1.x; acc[5] += b1.y; acc[6] += b1.z; acc[7] += b1.w;
        if (RELU) {
            #pragma unroll
            for (int j = 0; j < 8; j++) acc[j] = fmaxf(acc[j], 0.f);
        }
        uint4 o;
        o.x = (unsigned int)f2bf(acc[0]) | ((unsigned int)f2bf(acc[1]) << 16);
        o.y = (unsigned int)f2bf(acc[2]) | ((unsigned int)f2bf(acc[3]) << 16);
        o.z = (unsigned int)f2bf(acc[4]) | ((unsigned int)f2bf(acc[5]) << 16);
        o.w = (unsigned int)f2bf(acc[6]) | ((unsigned int)f2bf(acc[7]) << 16);
        ((uint4*)outd)[(size_t)node * 16 + sl] = o;
    }
}

// F=40 (bf16 H, stride 32 dwords, 20 used): one wave/node, 3x 20-lane groups,
// predicated 6-slot iterations, shfl reduce, lanes 0-19 store f32 float2.
__global__ __launch_bounds__(256) void gather40v2_kernel(
        const unsigned int* __restrict__ H,   // N x 32 dwords (20 used)
        const int* __restrict__ rowptr,
        const unsigned long long* __restrict__ edges,
        const float* __restrict__ dinv, const float* __restrict__ bias,
        float* __restrict__ out, int n) {
    int wave = threadIdx.x >> 6;
    int lane = threadIdx.x & 63;
    int node = blockIdx.x * 4 + wave;
    if (node >= n) return;
    int beg = __builtin_amdgcn_readfirstlane(rowptr[node]);
    int end = __builtin_amdgcn_readfirstlane(rowptr[node + 1]);
    int deg = end - beg;
    float di = dinv[node];
    int g = lane / 20;            // 0..3 (g==3: lanes 60-63, always predicated off)
    int sl = lane - g * 20;
    bool gv = g < 3;
    int slcl = gv ? sl : 0;

    unsigned int us = H[(size_t)node * 32 + slcl];
    float ws = (g == 0) ? di * di : 0.f;
    float ax = 0.f, ay = 0.f;

    for (int base = 0; base < deg; base += 6) {
        #pragma unroll
        for (int u = 0; u < 2; u++) {
            int slot = base + g * 2 + u;
            bool real = gv && (slot < deg);
            unsigned long long rec = edges[real ? (beg + slot) : 0];
            int s  = real ? (int)(unsigned int)rec : node;
            float w = real ? __uint_as_float((unsigned int)(rec >> 32)) : 0.f;
            unsigned int uu = H[(size_t)s * 32 + slcl];
            ax += w * bflo(uu);
            ay += w * bfhi(uu);
        }
    }
    ax += ws * bflo(us);
    ay += ws * bfhi(us);

    // reduce groups 1,2 into group 0 (read original values before updating)
    float ax1 = __shfl(ax, lane + 20), ay1 = __shfl(ay, lane + 20);
    float ax2 = __shfl(ax, lane + 40), ay2 = __shfl(ay, lane + 40);
    if (lane < 20) {
        ax += ax1 + ax2;
        ay += ay1 + ay2;
        float2 bv = ((const float2*)bias)[lane];
        ax += bv.x; ay += bv.y;
        *(float2*)&out[(size_t)node * 40 + 2 * lane] = make_float2(ax, ay);
    }
}

// ---------------- launch ----------------

extern "C" void kernel_launch(void* const* d_in, const int* in_sizes, int n_in,
                              void* d_out, int out_size, void* d_ws, size_t ws_size,
                              hipStream_t stream) {
    const float* x  = (const float*)d_in[0];
    const int*   ei = (const int*)d_in[1];
    const float* ew = (const float*)d_in[2];
    const float* W1 = (const float*)d_in[3];
    const float* b1 = (const float*)d_in[4];
    const float* W2 = (const float*)d_in[5];
    const float* b2 = (const float*)d_in[6];
    const float* W3 = (const float*)d_in[7];
    const float* b3 = (const float*)d_in[8];
    float* out = (float*)d_out;

    const int N = N_NODES, E = N_EDGES;
    const int* src = ei;
    const int* dst = ei + E;

    char* p = (char*)d_ws;
    unsigned long long* packed = (unsigned long long*)p; p += 800000;   // N u64
    float* dinv   = (float*)p; p += 400000;
    int*   cnt    = (int*)p;   p += 400000;
    int*   rowptr = (int*)p;   p += 400016;
    int*   bsum   = (int*)p;   p += 2048;
    int*   rank   = (int*)p;   p += 6400000;                            // E i32
    unsigned long long* edges = (unsigned long long*)p; p += 12800000;  // E u64
    void*  A      = (void*)p;  p += (size_t)N * 128 * 2;                // bf16 H
    void*  B      = (void*)p;                                           // bf16 layer output

    int nb = (N + 255) / 256;
    int eb = (E + 255) / 256;

    init_packed_kernel<<<nb, 256, 0, stream>>>(packed, N);
    edge_pass1_kernel<<<eb, 256, 0, stream>>>(dst, ew, packed, rank, E);
    scan1_kernel<<<SCAN_NB, 256, 0, stream>>>(packed, cnt, dinv, bsum, N);
    scan2_kernel<<<1, 512, 0, stream>>>(bsum, SCAN_NB);
    scan3_kernel<<<SCAN_NB, 256, 0, stream>>>(cnt, bsum, rowptr, N);
    place_kernel<<<eb, 256, 0, stream>>>(src, dst, ew, dinv, rowptr, rank, edges, E);

    int gemmb = (N + 127) / 128;   // 782
    int gb = (N + 3) / 4;

    // layer 1: A(bf16) = x(f32)@W1  [3-pass split]
    gemm_mfma_kernel<8, 128, 128, true><<<gemmb, 256, 0, stream>>>(x, W1, (unsigned short*)A, N);
    gather128v2_kernel<true><<<gb, 256, 0, stream>>>((const unsigned int*)A, rowptr, edges, dinv, b1, (unsigned int*)B, N);
    // layer 2: bf16 A, 2-pass W split
    gemm_mfma_kernel<8, 128, 128, false><<<gemmb, 256, 0, stream>>>(B, W2, (unsigned short*)A, N);
    gather128v2_kernel<true><<<gb, 256, 0, stream>>>((const unsigned int*)A, rowptr, edges, dinv, b2, (unsigned int*)B, N);
    // layer 3: FOUT=40 padded to 48 cols, H3 stride 64 shorts
    gemm_mfma_kernel<3, 40, 64, false><<<gemmb, 256, 0, stream>>>(B, W3, (unsigned short*)A, N);
    gather40v2_kernel<<<gb, 256, 0, stream>>>((const unsigned int*)A, rowptr, edges, dinv, b3, out, N);
}